// Round 1
// baseline (5530.824 us; speedup 1.0000x reference)
//
#include <hip/hip_runtime.h>

// Seq2Seq LSTM (B=2048, T=100, E=512, FUTURE=10, POSE=34). FP32 in/out.
// R10: PERSISTENT RECURRENCE. The whole encoder (cell1(0)..cell2(99)) runs in
// ONE cooperative kernel, 101 iterations, custom relaxed-atomic grid barrier.
//  - No per-step kernel launches (was 99+2) -> no dispatch/drain/ramp tax.
//  - Barrier does NOT flush/invalidate L2: weights stay L2-resident across all
//    steps (per-XCD slice ~800KB; natural xcd = e16%8 pinning).
//  - h-state exchange is the only cross-XCD traffic: producers store with
//    sc0 sc1 (write-through past L2), consumers use agent-scope relaxed
//    atomic loads (sc1, L2-bypass). Correct without buffer_inv.
//  - c1/c2 live in VGPRs (16 floats/thread) for all 100 steps; c2 is written
//    to global only at the last iteration (decoder needs it).
// Tiling/phases per iteration are unchanged from R9's fused kernel:
// 256 blocks = 16 e-slices x 16 R-groups; 8 waves = es2 x rb x cs;
// cs0 = cell1 (x@M1 + 8 Whh1 chunks), cs1 = cell2 (8 Wih2, then 8 Whh2).
// Decoder (10 steps) + out_proj unchanged (R8 per-cell kernel).

#define TSEQ 100
#define FUT 10
#define POSE_D 34
#define EDIM 512
#define BDIM 2048

typedef __bf16 bf16x8 __attribute__((ext_vector_type(8)));
typedef float floatx4 __attribute__((ext_vector_type(4)));
typedef short shortx8 __attribute__((ext_vector_type(8)));

__device__ __forceinline__ float bf2f(short s) {
    unsigned int u = ((unsigned int)(unsigned short)s) << 16;
    float f;
    __builtin_memcpy(&f, &u, 4);
    return f;
}
__device__ __forceinline__ short f2bf(float f) {
    unsigned int u;
    __builtin_memcpy(&u, &f, 4);
    u += 0x7fffu + ((u >> 16) & 1u);
    return (short)(u >> 16);
}
__device__ __forceinline__ float fsig(float x) { return 1.f / (1.f + __expf(-x)); }
__device__ __forceinline__ float ftanh(float x) {
    float ax = fabsf(x);
    float t = __expf(-2.f * ax);
    float r = (1.f - t) / (1.f + t);
    return x < 0.f ? -r : r;
}

// Swizzled W stream (1KB wave units):
//   unit(e0,kcp,es,g,kk) = (((e0*16+kcp)*4+es)*4+g)*2+kk ; shorts = unit*512+lane*8
//   src row = g*512 + e0*64 + es*16 + (lane&15), k = (kcp&7)*64 + kk*32 + (lane>>4)*8

// ---------------- persistent encoder kernel ----------------
__global__ __launch_bounds__(512, 2) void seq_persistent(
    const float* __restrict__ x, const short* __restrict__ M1,
    const short* __restrict__ sWhh1, const short* __restrict__ sWih2,
    const short* __restrict__ sWhh2, const float* __restrict__ bias1,
    const float* __restrict__ bias2, short* __restrict__ h1a,
    short* __restrict__ h1b, short* __restrict__ h2a, short* __restrict__ h2b,
    float* __restrict__ c2out, unsigned int* __restrict__ cnt) {
    __shared__ __align__(16) short lds[73728];  // x 16KB | panel 128KB
    const int tid = threadIdx.x;
    const int lane = tid & 63;
    const int wv = tid >> 6;
    const int es2 = wv & 1;
    const int rb = (wv >> 1) & 1;
    const int cs = wv >> 2;  // 0 -> cell1, 1 -> cell2
    const int m = lane & 15;
    const int q = lane >> 4;
    const int e16 = blockIdx.x & 15;
    const int R0 = (blockIdx.x >> 4) * 128;
    const int e0 = e16 >> 1;
    const int es = (e16 & 1) * 2 + es2;
    constexpr int AOFF = 8192;

    // persistent cell state: cs0 threads hold c1 slice, cs1 threads hold c2.
    float creg[16];
#pragma unroll
    for (int i = 0; i < 16; ++i) creg[i] = 0.f;

    floatx4 acc[4][4];
    bf16x8 rW0[8], rW1[8];

    auto loadW = [&](const short* __restrict__ W, int kcp, bf16x8(&w_)[8]) {
        const short* P = W + (long)((e0 * 16 + kcp) * 4 + es) * 4096 + lane * 8;
#pragma unroll
        for (int i = 0; i < 8; ++i) w_[i] = *(const bf16x8*)(P + i * 512);
    };
    auto do_chunk = [&](int kcp, bf16x8(&w_)[8]) {
        const int k8 = (kcp & 7) * 8;
#pragma unroll
        for (int kk = 0; kk < 2; ++kk) {
            bf16x8 a[4];
#pragma unroll
            for (int ri = 0; ri < 4; ++ri) {
                const int row = rb * 64 + ri * 16 + m;
                a[ri] = *(const bf16x8*)(lds + AOFF + row * 512 +
                                         ((k8 | (((kk * 4 + q) ^ row) & 7)) << 3));
            }
#pragma unroll
            for (int ri = 0; ri < 4; ++ri)
#pragma unroll
                for (int g = 0; g < 4; ++g)
                    acc[ri][g] = __builtin_amdgcn_mfma_f32_16x16x32_bf16(
                        a[ri], w_[g * 2 + kk], acc[ri][g], 0, 0, 0);
        }
    };
    auto do_x = [&](bf16x8(&w_)[8]) {
#pragma unroll
        for (int kk = 0; kk < 2; ++kk) {
            bf16x8 a[4];
#pragma unroll
            for (int ri = 0; ri < 4; ++ri) {
                const int row = rb * 64 + ri * 16 + m;
                a[ri] = *(const bf16x8*)(lds + row * 64 + (((kk * 4 + q) ^ (row & 7)) << 3));
            }
#pragma unroll
            for (int ri = 0; ri < 4; ++ri)
#pragma unroll
                for (int g = 0; g < 4; ++g)
                    acc[ri][g] = __builtin_amdgcn_mfma_f32_16x16x32_bf16(
                        a[ri], w_[g * 2 + kk], acc[ri][g], 0, 0, 0);
        }
    };
    // h-panel stage: agent-scope (sc1) loads bypass L2 -> always coherent with
    // other XCDs' write-through h stores, without any cache invalidation.
    auto stageA = [&](const short* __restrict__ G) {
#pragma unroll
        for (int i = 0; i < 16; ++i) {
            const int u = tid + (i << 9);
            const int r = u >> 6, c = u & 63;
            const unsigned long long* s =
                (const unsigned long long*)(G + (long)r * 512 + (c << 3));
            unsigned long long v0 =
                __hip_atomic_load(s, __ATOMIC_RELAXED, __HIP_MEMORY_SCOPE_AGENT);
            unsigned long long v1 =
                __hip_atomic_load(s + 1, __ATOMIC_RELAXED, __HIP_MEMORY_SCOPE_AGENT);
            unsigned long long* d = (unsigned long long*)(
                lds + AOFF + r * 512 + (((c & 56) | ((c ^ r) & 7)) << 3));
            d[0] = v0;
            d[1] = v1;
        }
    };
    auto epilogue = [&](const float* __restrict__ bias, short* __restrict__ h_out,
                        float* __restrict__ c_out) {
        const int e = e16 * 32 + es2 * 16 + m;
        const float bi = bias[e];
        const float bfv = bias[512 + e];
        const float bg = bias[1024 + e];
        const float bo = bias[1536 + e];
#pragma unroll
        for (int ri = 0; ri < 4; ++ri) {
#pragma unroll
            for (int rg = 0; rg < 4; ++rg) {
                const int br = R0 + rb * 64 + ri * 16 + q * 4 + rg;  // C/D: row=q*4+reg
                const long cidx = (long)br * EDIM + e;
                const float iv = fsig(acc[ri][0][rg] + bi);
                const float fv = fsig(acc[ri][1][rg] + bfv);
                const float gv = ftanh(acc[ri][2][rg] + bg);
                const float ov = fsig(acc[ri][3][rg] + bo);
                float& cc = creg[ri * 4 + rg];
                const float cn = fv * cc + iv * gv;
                cc = cn;
                const int hvi = (int)f2bf(ov * ftanh(cn));
                // write-through past L2 (cross-XCD visible at L3)
                asm volatile("global_store_short %0, %1, off sc0 sc1" ::"v"(h_out + cidx),
                             "v"(hvi)
                             : "memory");
                if (c_out) c_out[cidx] = cn;
            }
        }
    };

    // zero the x pad region once (cols 34..63 stay zero forever)
    {
        floatx4 z = {0.f, 0.f, 0.f, 0.f};
        *(floatx4*)(lds + tid * 16) = z;
        *(floatx4*)(lds + tid * 16 + 8) = z;
    }
    __syncthreads();

    short* const h1buf[2] = {h1a, h1b};
    short* const h2buf[2] = {h2a, h2b};

    // iteration it: cell1(it) for it in [0,99]; cell2(it-1) for it in [1,100].
#pragma unroll 1
    for (int it = 0; it <= TSEQ; ++it) {
        const bool do1 = (it < TSEQ);
        const bool doh = (it >= 1);
        const short* rd1 = h1buf[(it & 1) ^ 1];  // h1(it-1)
        const short* rd2 = h2buf[it & 1];        // h2(it-2)
        short* wr1 = h1buf[it & 1];              // h1(it)
        short* wr2 = h2buf[(it & 1) ^ 1];        // h2(it-1)

        // ---- stage h1 panel + x slice; preload first W chunks ----
        if (doh) stageA(rd1 + (long)R0 * 512);
        if (do1) {
            const float* xit = x + (long)it * POSE_D;
            for (int idx = tid; idx < 128 * POSE_D; idx += 512) {
                const int r = idx / POSE_D;
                const int c = idx - r * POSE_D;
                lds[r * 64 + (((c >> 3) ^ (r & 7)) << 3) + (c & 7)] =
                    f2bf(xit[(long)(R0 + r) * (TSEQ * POSE_D) + c]);
            }
        }
        if (cs == 0) {
            if (do1) {
                const short* P = M1 + (long)((e0 * 4 + es) * 8) * 512 + lane * 8;
#pragma unroll
                for (int i = 0; i < 8; ++i) rW0[i] = *(const bf16x8*)(P + i * 512);
                if (doh) loadW(sWhh1, 0, rW1);
            }
        } else if (doh) {
            loadW(sWih2, 0, rW0);
            loadW(sWih2, 1, rW1);
        }
#pragma unroll
        for (int ri = 0; ri < 4; ++ri)
#pragma unroll
            for (int g = 0; g < 4; ++g) acc[ri][g] = {0.f, 0.f, 0.f, 0.f};
        __syncthreads();

        // ---- phase 1: both cells consume the h1 panel ----
        if (cs == 0) {
            if (do1) {
                do_x(rW0);  // gates1 += x(it) @ M1^T
                if (doh) {
#pragma unroll 1
                    for (int k = 0; k < 8; ++k) {  // gates1 += h1 @ Whh1^T
                        bf16x8(&buf)[8] = (k & 1) ? rW0 : rW1;
                        do_chunk(k, buf);
                        if (k + 2 < 8) loadW(sWhh1, k + 2, buf);
                    }
                }
            }
        } else if (doh) {
#pragma unroll 1
            for (int k = 0; k < 8; ++k) {  // gates2 += h1 @ Wih2^T
                bf16x8(&buf)[8] = (k & 1) ? rW1 : rW0;
                do_chunk(k, buf);
                if (k + 2 < 8) loadW(sWih2, k + 2, buf);
            }
        }

        // ---- re-stage panel with h2(it-2) ----
        __syncthreads();  // all h1-panel reads done
        if (doh) {
            stageA(rd2 + (long)R0 * 512);
            if (cs == 1) {
                loadW(sWhh2, 0, rW0);
                loadW(sWhh2, 1, rW1);
            }
        }
        __syncthreads();

        // ---- phase 2: cs1 finishes cell2 while cs0 writes cell1's state ----
        if (cs == 0) {
            if (do1) epilogue(bias1, wr1, nullptr);  // c1 stays in VGPRs
        } else if (doh) {
#pragma unroll 1
            for (int k = 0; k < 8; ++k) {  // gates2 += h2 @ Whh2^T
                bf16x8(&buf)[8] = (k & 1) ? rW1 : rW0;
                do_chunk(k, buf);
                if (k + 2 < 8) loadW(sWhh2, k + 2, buf);
            }
            epilogue(bias2, wr2, (it == TSEQ) ? c2out : nullptr);
        }

        // ---- grid barrier (no L2 flush/invalidate) ----
        if (it < TSEQ) {
            asm volatile("s_waitcnt vmcnt(0)" ::: "memory");  // h stores at L3
            __syncthreads();
            if (tid == 0) {
                __hip_atomic_fetch_add(cnt, 1u, __ATOMIC_RELAXED,
                                       __HIP_MEMORY_SCOPE_AGENT);
                const unsigned tgt = 256u * (unsigned)(it + 1);
                while (__hip_atomic_load(cnt, __ATOMIC_RELAXED,
                                         __HIP_MEMORY_SCOPE_AGENT) < tgt)
                    __builtin_amdgcn_s_sleep(2);
            }
            __syncthreads();
        }
    }
}

// ---------------- per-cell kernel (decoder), from R8 ----------------
template <bool HAS_X, bool TWO_H, int NP>
__global__ __launch_bounds__(512, 2) void lstm_cell_kernel(
    const float* __restrict__ xptr, const short* __restrict__ M1,
    const short* __restrict__ A1, const short* __restrict__ W1,
    const short* __restrict__ A2, const short* __restrict__ W2,
    const float* __restrict__ bias, float* __restrict__ c_io,
    short* __restrict__ h_out, float* __restrict__ hf_out) {
    __shared__ __align__(16) short lds[HAS_X ? 73728 : 65536];
    const int tid = threadIdx.x;
    const int lane = tid & 63;
    const int wv = tid >> 6;
    const int es2 = wv & 1;
    const int rb = (wv >> 1) & 1;
    const int kg = wv >> 2;
    const int m = lane & 15;
    const int q = lane >> 4;
    const int e16 = blockIdx.x & 15;
    const int R0 = (blockIdx.x >> 4) * 128;
    const int e0 = e16 >> 1;
    const int es = (e16 & 1) * 2 + es2;
    constexpr int PH = NP * 8;
    constexpr int AOFF = HAS_X ? 8192 : 0;

    floatx4 acc[4][4];
#pragma unroll
    for (int ri = 0; ri < 4; ++ri)
#pragma unroll
        for (int g = 0; g < 4; ++g) acc[ri][g] = {0.f, 0.f, 0.f, 0.f};

    bf16x8 rW0[8], rW1[8];

    auto loadW = [&](const short* __restrict__ W, int kcp, bf16x8(&w_)[8]) {
        const short* P = W + (long)((e0 * 16 + kcp) * 4 + es) * 4096 + lane * 8;
#pragma unroll
        for (int i = 0; i < 8; ++i) w_[i] = *(const bf16x8*)(P + i * 512);
    };
    auto loadM1 = [&](bf16x8(&w_)[8]) {
        const short* P = M1 + (long)((e0 * 4 + es) * 8) * 512 + lane * 8;
#pragma unroll
        for (int i = 0; i < 8; ++i) w_[i] = *(const bf16x8*)(P + i * 512);
    };
    auto do_chunk = [&](int kcp, bf16x8(&w_)[8]) {
        const int k8 = (kcp & 7) * 8;
#pragma unroll
        for (int kk = 0; kk < 2; ++kk) {
            bf16x8 a[4];
#pragma unroll
            for (int ri = 0; ri < 4; ++ri) {
                const int row = rb * 64 + ri * 16 + m;
                a[ri] = *(const bf16x8*)(lds + AOFF + row * 512 +
                                         ((k8 | (((kk * 4 + q) ^ row) & 7)) << 3));
            }
#pragma unroll
            for (int ri = 0; ri < 4; ++ri)
#pragma unroll
                for (int g = 0; g < 4; ++g)
                    acc[ri][g] = __builtin_amdgcn_mfma_f32_16x16x32_bf16(
                        a[ri], w_[g * 2 + kk], acc[ri][g], 0, 0, 0);
        }
    };
    auto do_x = [&](bf16x8(&w_)[8]) {
#pragma unroll
        for (int kk = 0; kk < 2; ++kk) {
            bf16x8 a[4];
#pragma unroll
            for (int ri = 0; ri < 4; ++ri) {
                const int row = rb * 64 + ri * 16 + m;
                a[ri] = *(const bf16x8*)(lds + row * 64 + (((kk * 4 + q) ^ (row & 7)) << 3));
            }
#pragma unroll
            for (int ri = 0; ri < 4; ++ri)
#pragma unroll
                for (int g = 0; g < 4; ++g)
                    acc[ri][g] = __builtin_amdgcn_mfma_f32_16x16x32_bf16(
                        a[ri], w_[g * 2 + kk], acc[ri][g], 0, 0, 0);
        }
    };
    auto stageA = [&](const short* __restrict__ G, int dst) {
#pragma unroll
        for (int i = 0; i < 16; ++i) {
            const int u = tid + (i << 9);
            const int r = u >> 6, c = u & 63;
            const shortx8 v = *(const shortx8*)(G + (long)r * 512 + (c << 3));
            *(shortx8*)(lds + dst + r * 512 + (((c & 56) | ((c ^ r) & 7)) << 3)) = v;
        }
    };
    auto loopP = [&](const short* __restrict__ W) {
        int c = kg;
#pragma unroll 1
        for (;;) {
            const int nxt = c + 2;
            if (nxt < PH) loadW(W, nxt, rW1);
            do_chunk(c, rW0);
            c = nxt;
            if (c >= PH) break;
            const int nx2 = c + 2;
            if (nx2 < PH) loadW(W, nx2, rW0);
            do_chunk(c, rW1);
            c = nx2;
            if (c >= PH) break;
        }
    };

    if constexpr (HAS_X) {
        constexpr int NT = 1 + PH;
        floatx4 z = {0.f, 0.f, 0.f, 0.f};
        *(floatx4*)(lds + tid * 16) = z;
        *(floatx4*)(lds + tid * 16 + 8) = z;
        stageA(A1 + (long)R0 * 512, AOFF);
        __syncthreads();
        for (int idx = tid; idx < 128 * POSE_D; idx += 512) {
            const int r = idx / POSE_D;
            const int c = idx - r * POSE_D;
            lds[r * 64 + (((c >> 3) ^ (r & 7)) << 3) + (c & 7)] =
                f2bf(xptr[(long)(R0 + r) * (TSEQ * POSE_D) + c]);
        }
        if (kg == 0) loadM1(rW0);
        else loadW(W1, 0, rW0);
        __syncthreads();
        int c = kg;
#pragma unroll 1
        for (;;) {
            const int nxt = c + 2;
            if (nxt < NT) loadW(W1, nxt - 1, rW1);
            if (c == 0) do_x(rW0);
            else do_chunk(c - 1, rW0);
            c = nxt;
            if (c >= NT) break;
            const int nx2 = c + 2;
            if (nx2 < NT) loadW(W1, nx2 - 1, rW0);
            do_chunk(c - 1, rW1);
            c = nx2;
            if (c >= NT) break;
        }
    } else {
        stageA(A1 + (long)R0 * 512, AOFF);
        loadW(W1, kg, rW0);
        __syncthreads();
        loopP(W1);
        if constexpr (TWO_H) {
            __syncthreads();
            stageA(A2 + (long)R0 * 512, AOFF);
            loadW(W2, kg, rW0);
            __syncthreads();
            loopP(W2);
        }
    }

    __syncthreads();
    float* ldsf = (float*)lds;
    const int L = (rb * 2 + es2) * 64 + lane;
    if (kg == 1) {
#pragma unroll
        for (int ri = 0; ri < 4; ++ri)
#pragma unroll
            for (int g = 0; g < 4; ++g) {
                const int f4 = ri * 4 + g;
                *(floatx4*)(ldsf + L * 68 + ((f4 ^ m) << 2)) = acc[ri][g];
            }
    }
    __syncthreads();
    if (kg == 0) {
#pragma unroll
        for (int ri = 0; ri < 4; ++ri)
#pragma unroll
            for (int g = 0; g < 4; ++g) {
                const int f4 = ri * 4 + g;
                acc[ri][g] += *(const floatx4*)(ldsf + L * 68 + ((f4 ^ m) << 2));
            }
        const int e = e16 * 32 + es2 * 16 + m;
        const float bi = bias[e];
        const float bfv = bias[512 + e];
        const float bg = bias[1024 + e];
        const float bo = bias[1536 + e];
#pragma unroll
        for (int ri = 0; ri < 4; ++ri) {
#pragma unroll
            for (int rg = 0; rg < 4; ++rg) {
                const int br = R0 + rb * 64 + ri * 16 + q * 4 + rg;
                const long cidx = (long)br * EDIM + e;
                const float iv = fsig(acc[ri][0][rg] + bi);
                const float fv = fsig(acc[ri][1][rg] + bfv);
                const float gv = ftanh(acc[ri][2][rg] + bg);
                const float ov = fsig(acc[ri][3][rg] + bo);
                const float cn = fv * c_io[cidx] + iv * gv;
                c_io[cidx] = cn;
                const float hv = ov * ftanh(cn);
                h_out[cidx] = f2bf(hv);
                if (hf_out) hf_out[cidx] = hv;
            }
        }
    }
}

__global__ __launch_bounds__(256) void zero_kernel(unsigned int* __restrict__ p, int n) {
    int i = blockIdx.x * 256 + threadIdx.x;
    const int stride = gridDim.x * 256;
    for (; i < n; i += stride) p[i] = 0u;
}

__global__ __launch_bounds__(256) void prep_bias(
    const float* __restrict__ bih1, const float* __restrict__ bhh1,
    const float* __restrict__ Wih1, const float* __restrict__ encb,
    const float* __restrict__ bih2, const float* __restrict__ bhh2,
    const float* __restrict__ dbih, const float* __restrict__ dbhh,
    float* __restrict__ bias1, float* __restrict__ bias2, float* __restrict__ biasd) {
    const int n = blockIdx.x * 256 + threadIdx.x;
    if (n >= 2048) return;
    float s = bih1[n] + bhh1[n];
    const float* wr = Wih1 + (long)n * EDIM;
    for (int j = 0; j < EDIM; ++j) s += wr[j] * encb[j];
    bias1[n] = s;
    bias2[n] = bih2[n] + bhh2[n];
    biasd[n] = dbih[n] + dbhh[n];
}

// Swizzle fp32 W[2048x512] (+optional addend) into hi|lo bf16 frag-stream;
// nkc limits chunk planes written (8 = hi only, 16 = hi+lo).
__global__ __launch_bounds__(256) void swizzle_w(const float* __restrict__ a,
                                                 const float* __restrict__ b,
                                                 short* __restrict__ o, int nkc) {
    const int idx = blockIdx.x * 256 + threadIdx.x;
    if (idx >= 262144) return;
    const int lane = idx & 63, kk = (idx >> 6) & 1, g = (idx >> 7) & 3;
    const int w = (idx >> 9) & 3, kc = (idx >> 11) & 15, e0 = idx >> 15;
    if (kc >= nkc) return;
    const int row = g * 512 + e0 * 64 + w * 16 + (lane & 15);
    const int ks = (kc & 7) * 64 + kk * 32 + (lane >> 4) * 8;
    const bool lo = kc >= 8;
    shortx8 outv;
#pragma unroll
    for (int j = 0; j < 8; ++j) {
        const long si = (long)row * EDIM + ks + j;
        const float v = b ? (a[si] + b[si]) : a[si];
        const short hi = f2bf(v);
        outv[j] = lo ? f2bf(v - bf2f(hi)) : hi;
    }
    *(shortx8*)(o + (long)idx * 8) = outv;
}

__global__ __launch_bounds__(256) void swizzle_M1(const float* __restrict__ Wih1,
                                                  const float* __restrict__ encW,
                                                  short* __restrict__ o) {
    const int idx = blockIdx.x * 256 + threadIdx.x;
    if (idx >= 131072) return;
    const int u = idx >> 3, j = idx & 7;
    const int lane = u & 63, kk = (u >> 6) & 1, g = (u >> 7) & 3;
    const int w = (u >> 9) & 3, e0 = u >> 11;
    const int row = g * 512 + e0 * 64 + w * 16 + (lane & 15);
    const int k = kk * 32 + (lane >> 4) * 8 + j;
    float s = 0.f;
    if (k < POSE_D) {
        const float* wr = Wih1 + (long)row * EDIM;
        for (int jj = 0; jj < EDIM; ++jj) s += wr[jj] * encW[jj * POSE_D + k];
    }
    o[(long)u * 8 + j] = f2bf(s);
}

__global__ __launch_bounds__(64) void out_proj(const float* __restrict__ hf,
                                               const float* __restrict__ W,
                                               const float* __restrict__ bias,
                                               float* __restrict__ out, int f) {
    const int b = blockIdx.x;
    __shared__ float hrow[EDIM];
    const int lane = threadIdx.x;
    *(floatx4*)(hrow + lane * 8) = *(const floatx4*)(hf + (long)b * EDIM + lane * 8);
    *(floatx4*)(hrow + lane * 8 + 4) = *(const floatx4*)(hf + (long)b * EDIM + lane * 8 + 4);
    __syncthreads();
    if (lane < POSE_D) {
        float acc = bias[lane];
        const float* wr = W + (long)lane * EDIM;
        for (int e = 0; e < EDIM; e += 4) {
            const floatx4 wv = *(const floatx4*)(wr + e);
            acc += hrow[e] * wv[0] + hrow[e + 1] * wv[1] + hrow[e + 2] * wv[2] + hrow[e + 3] * wv[3];
        }
        out[((long)b * FUT + f) * POSE_D + lane] = acc;
    }
}

extern "C" void kernel_launch(void* const* d_in, const int* in_sizes, int n_in,
                              void* d_out, int out_size, void* d_ws, size_t ws_size,
                              hipStream_t stream) {
    const float* x = (const float*)d_in[0];
    const float* encW = (const float*)d_in[1];
    const float* encb = (const float*)d_in[2];
    const float* Wih1 = (const float*)d_in[3];
    const float* Whh1 = (const float*)d_in[4];
    const float* bih1 = (const float*)d_in[5];
    const float* bhh1 = (const float*)d_in[6];
    const float* Wih2 = (const float*)d_in[7];
    const float* Whh2 = (const float*)d_in[8];
    const float* bih2 = (const float*)d_in[9];
    const float* bhh2 = (const float*)d_in[10];
    const float* dWih = (const float*)d_in[11];
    const float* dWhh = (const float*)d_in[12];
    const float* dbih = (const float*)d_in[13];
    const float* dbhh = (const float*)d_in[14];
    const float* oW = (const float*)d_in[15];
    const float* ob = (const float*)d_in[16];
    float* out = (float*)d_out;

    char* ws = (char*)d_ws;
    size_t off = 0;
    auto alloc = [&](size_t bytes) -> char* {
        char* p = ws + off;
        off = (off + bytes + 255) & ~(size_t)255;
        return p;
    };
    const size_t HB = (size_t)BDIM * EDIM * 2;
    const size_t CB = (size_t)BDIM * EDIM * 4;
    const size_t WSZ = (size_t)262144 * 16;
    // zero-region (contiguous): h2b (read as h2(-1) zeros), barrier counter
    short* h2b = (short*)alloc(HB);
    unsigned int* cnt = (unsigned int*)alloc(256);
    short* h1a = (short*)alloc(HB);
    short* h1b = (short*)alloc(HB);
    short* h2a = (short*)alloc(HB);
    float* c2 = (float*)alloc(CB);
    float* hf0 = (float*)alloc(CB);
    float* hf1 = (float*)alloc(CB);
    short* M1 = (short*)alloc((size_t)16384 * 16);
    short* sWhh1 = (short*)alloc(WSZ);
    short* sWih2 = (short*)alloc(WSZ);
    short* sWhh2 = (short*)alloc(WSZ);
    short* sdWhh = (short*)alloc(WSZ);
    short* sWsum = (short*)alloc(WSZ);
    float* bias1 = (float*)alloc(2048 * 4);
    float* bias2 = (float*)alloc(2048 * 4);
    float* biasd = (float*)alloc(2048 * 4);
    (void)ws_size; (void)in_sizes; (void)n_in; (void)out_size;

    zero_kernel<<<2048, 256, 0, stream>>>((unsigned int*)h2b, (int)((HB + 256) / 4));
    prep_bias<<<8, 256, 0, stream>>>(bih1, bhh1, Wih1, encb, bih2, bhh2, dbih, dbhh,
                                     bias1, bias2, biasd);
    swizzle_M1<<<512, 256, 0, stream>>>(Wih1, encW, M1);
    swizzle_w<<<1024, 256, 0, stream>>>(Whh1, nullptr, sWhh1, 8);
    swizzle_w<<<1024, 256, 0, stream>>>(Wih2, nullptr, sWih2, 8);
    swizzle_w<<<1024, 256, 0, stream>>>(Whh2, nullptr, sWhh2, 8);
    swizzle_w<<<1024, 256, 0, stream>>>(dWhh, nullptr, sdWhh, 16);
    swizzle_w<<<1024, 256, 0, stream>>>(dWih, dWhh, sWsum, 16);

    // ---- whole encoder recurrence: one persistent cooperative kernel ----
    {
        void* kargs[] = {&x,     &M1,    &sWhh1, &sWih2, &sWhh2, &bias1, &bias2,
                         &h1a,   &h1b,   &h2a,   &h2b,   &c2,    &cnt};
        if (hipLaunchCooperativeKernel((void*)seq_persistent, dim3(256), dim3(512),
                                       kargs, 0, stream) != hipSuccess) {
            // grid=256, 144KB LDS -> 1 block/CU -> co-resident by construction
            seq_persistent<<<dim3(256), dim3(512), 0, stream>>>(
                x, M1, sWhh1, sWih2, sWhh2, bias1, bias2, h1a, h1b, h2a, h2b, c2, cnt);
        }
    }
    // h2(99) is in h2b (written at it=100); c2(99) in c2.

    dim3 grid(256), blk(512);
    // decoder (split weights): bf16 ping-pong + fp32 copies for out_proj
    short* hd0 = h1a;
    short* hd1 = h1b;
    lstm_cell_kernel<false, false, 2><<<grid, blk, 0, stream>>>(
        nullptr, nullptr, h2b, sdWhh, nullptr, nullptr, biasd, c2, hd0, hf0);
    out_proj<<<BDIM, 64, 0, stream>>>(hf0, oW, ob, out, 0);
    short *dp = hd0, *dn = hd1;
    float *fp = hf0, *fn = hf1;
    for (int f = 1; f < FUT; ++f) {
        lstm_cell_kernel<false, false, 2><<<grid, blk, 0, stream>>>(
            nullptr, nullptr, dp, sWsum, nullptr, nullptr, biasd, c2, dn, fn);
        out_proj<<<BDIM, 64, 0, stream>>>(fn, oW, ob, out, f);
        short* tt = dp; dp = dn; dn = tt;
        float* tf = fp; fp = fn; fn = tf;
    }
}

// Round 2
// 5076.736 us; speedup vs baseline: 1.0894x; 1.0894x over previous
//
#include <hip/hip_runtime.h>

// Seq2Seq LSTM (B=2048, T=100, E=512, FUTURE=10, POSE=34). FP32 in/out.
// R11: PERSISTENT RECURRENCE, fabric-tuned. R10 post-mortem: 46 MB/iter of
// 8-byte L2-bypass h-panel requests ran at ~1 TB/s = the whole runtime.
// Fixes:
//  - Geometry 64 rows x 64 e-cols per block (was 128x32): h-panel bypass
//    volume halves (32 MB/iter); W e-slice per block = one e0 unit -> per-XCD
//    W footprint ~830KB, L2-resident under round-robin dispatch (perf-only
//    assumption; correctness uses only write-through stores + bypass loads).
//  - Panel staging via inline-asm global_load_dwordx4 sc0 sc1: 16B/lane,
//    1KB contiguous per wave-instruction -> coalesced 64B fabric requests.
//  - LDS holds x(8K) + panelA(64K) + panelB(64K): h2 panel is issued at the
//    top of phase 1 and its latency hides under the phase-1 MFMA stream.
//  - c1/c2 stay in VGPRs across all 100 steps (c2 written once at the end).
// Swizzled W stream layout is UNCHANGED (indexed by e0 in [0,8), es in [0,4));
// only block/wave index derivation changed. Decoder kernels unchanged.

#define TSEQ 100
#define FUT 10
#define POSE_D 34
#define EDIM 512
#define BDIM 2048

typedef __bf16 bf16x8 __attribute__((ext_vector_type(8)));
typedef float floatx4 __attribute__((ext_vector_type(4)));
typedef short shortx8 __attribute__((ext_vector_type(8)));

__device__ __forceinline__ float bf2f(short s) {
    unsigned int u = ((unsigned int)(unsigned short)s) << 16;
    float f;
    __builtin_memcpy(&f, &u, 4);
    return f;
}
__device__ __forceinline__ short f2bf(float f) {
    unsigned int u;
    __builtin_memcpy(&u, &f, 4);
    u += 0x7fffu + ((u >> 16) & 1u);
    return (short)(u >> 16);
}
__device__ __forceinline__ float fsig(float x) { return 1.f / (1.f + __expf(-x)); }
__device__ __forceinline__ float ftanh(float x) {
    float ax = fabsf(x);
    float t = __expf(-2.f * ax);
    float r = (1.f - t) / (1.f + t);
    return x < 0.f ? -r : r;
}

// Swizzled W stream (1KB wave units):
//   unit(e0,kcp,es,g,kk) = (((e0*16+kcp)*4+es)*4+g)*2+kk ; shorts = unit*512+lane*8
//   src row = g*512 + e0*64 + es*16 + (lane&15), k = (kcp&7)*64 + kk*32 + (lane>>4)*8

// ---------------- persistent encoder kernel ----------------
__global__ __launch_bounds__(512, 2) void seq_persistent(
    const float* __restrict__ x, const short* __restrict__ M1,
    const short* __restrict__ sWhh1, const short* __restrict__ sWih2,
    const short* __restrict__ sWhh2, const float* __restrict__ bias1,
    const float* __restrict__ bias2, short* __restrict__ h1a,
    short* __restrict__ h1b, short* __restrict__ h2a, short* __restrict__ h2b,
    float* __restrict__ c2out, unsigned int* __restrict__ cnt) {
    // x: 64x64 (4096 shorts) | panel A: 64x512 (32768) | panel B: 64x512
    __shared__ __align__(16) short lds[69632];  // 136 KB
    const int tid = threadIdx.x;
    const int lane = tid & 63;
    const int wv = tid >> 6;
    const int es = wv & 3;   // 16-col quarter of the block's 64-col e-slice
    const int cs = wv >> 2;  // 0 -> cell1, 1 -> cell2
    const int m = lane & 15;
    const int q = lane >> 4;
    const int e0 = blockIdx.x & 7;          // 64-col e-slice (XCD-pinned under RR)
    const int R0 = (blockIdx.x >> 3) * 64;  // 64-row batch slice
    constexpr int XOFF = 0;
    constexpr int AOFF = 4096;
    constexpr int BOFF = 36864;

    // persistent cell state: cs0 threads hold c1 slice, cs1 threads hold c2.
    float creg[16];
#pragma unroll
    for (int i = 0; i < 16; ++i) creg[i] = 0.f;

    floatx4 acc[4][4];
    bf16x8 rW0[8], rW1[8];
    floatx4 pan[8];  // panel staging registers (bypass loads land here)

    auto loadW = [&](const short* __restrict__ W, int kcp, bf16x8(&w_)[8]) {
        const short* P = W + (long)((e0 * 16 + kcp) * 4 + es) * 4096 + lane * 8;
#pragma unroll
        for (int i = 0; i < 8; ++i) w_[i] = *(const bf16x8*)(P + i * 512);
    };
    auto do_chunk = [&](int kcp, bf16x8(&w_)[8], int off) {
        const int k8 = (kcp & 7) * 8;
#pragma unroll
        for (int kk = 0; kk < 2; ++kk) {
            bf16x8 a[4];
#pragma unroll
            for (int ri = 0; ri < 4; ++ri) {
                const int row = ri * 16 + m;
                a[ri] = *(const bf16x8*)(lds + off + row * 512 +
                                         ((k8 | (((kk * 4 + q) ^ row) & 7)) << 3));
            }
#pragma unroll
            for (int ri = 0; ri < 4; ++ri)
#pragma unroll
                for (int g = 0; g < 4; ++g)
                    acc[ri][g] = __builtin_amdgcn_mfma_f32_16x16x32_bf16(
                        a[ri], w_[g * 2 + kk], acc[ri][g], 0, 0, 0);
        }
    };
    auto do_x = [&](bf16x8(&w_)[8]) {
#pragma unroll
        for (int kk = 0; kk < 2; ++kk) {
            bf16x8 a[4];
#pragma unroll
            for (int ri = 0; ri < 4; ++ri) {
                const int row = ri * 16 + m;
                a[ri] = *(const bf16x8*)(lds + XOFF + row * 64 +
                                         (((kk * 4 + q) ^ (row & 7)) << 3));
            }
#pragma unroll
            for (int ri = 0; ri < 4; ++ri)
#pragma unroll
                for (int g = 0; g < 4; ++g)
                    acc[ri][g] = __builtin_amdgcn_mfma_f32_16x16x32_bf16(
                        a[ri], w_[g * 2 + kk], acc[ri][g], 0, 0, 0);
        }
    };
    // issue 8 x dwordx4 bypass loads (system scope: coherent with other XCDs'
    // write-through h stores). 1KB contiguous per wave-instruction.
    auto issue_panel = [&](const short* __restrict__ G) {
#pragma unroll
        for (int i = 0; i < 8; ++i) {
            const int u = tid + (i << 9);  // 16B unit index
            const short* s = G + (long)u * 8;
            asm volatile("global_load_dwordx4 %0, %1, off sc0 sc1"
                         : "=v"(pan[i])
                         : "v"(s)
                         : "memory");
        }
    };
    // drain the asm loads, then swizzle-write the panel into LDS.
    auto write_panel = [&](int off) {
        asm volatile("s_waitcnt vmcnt(0)" ::: "memory");
        __builtin_amdgcn_sched_barrier(0);
#pragma unroll
        for (int i = 0; i < 8; ++i) {
            const int u = tid + (i << 9);
            const int r = u >> 6, c = u & 63;
            *(floatx4*)(lds + off + r * 512 + (((c & 56) | ((c ^ r) & 7)) << 3)) =
                pan[i];
        }
    };
    auto epilogue = [&](const float* __restrict__ bias, short* __restrict__ h_out,
                        float* __restrict__ c_out) {
        const int e = e0 * 64 + es * 16 + m;
        const float bi = bias[e];
        const float bfv = bias[512 + e];
        const float bg = bias[1024 + e];
        const float bo = bias[1536 + e];
#pragma unroll
        for (int ri = 0; ri < 4; ++ri) {
#pragma unroll
            for (int rg = 0; rg < 4; ++rg) {
                const int br = R0 + ri * 16 + q * 4 + rg;  // C/D: row=q*4+reg
                const long cidx = (long)br * EDIM + e;
                const float iv = fsig(acc[ri][0][rg] + bi);
                const float fv = fsig(acc[ri][1][rg] + bfv);
                const float gv = ftanh(acc[ri][2][rg] + bg);
                const float ov = fsig(acc[ri][3][rg] + bo);
                float& cc = creg[ri * 4 + rg];
                const float cn = fv * cc + iv * gv;
                cc = cn;
                const int hvi = (int)f2bf(ov * ftanh(cn));
                // write-through past L2 (cross-XCD visible at L3)
                asm volatile("global_store_short %0, %1, off sc0 sc1" ::"v"(h_out + cidx),
                             "v"(hvi)
                             : "memory");
                if (c_out) c_out[cidx] = cn;
            }
        }
    };

    // zero the x pad region once (cols 34..63 stay zero forever)
    {
        floatx4 z = {0.f, 0.f, 0.f, 0.f};
        *(floatx4*)(lds + XOFF + tid * 8) = z;
    }
    __syncthreads();

    short* const h1buf[2] = {h1a, h1b};
    short* const h2buf[2] = {h2a, h2b};

    // iteration it: cell1(it) for it in [0,99]; cell2(it-1) for it in [1,100].
#pragma unroll 1
    for (int it = 0; it <= TSEQ; ++it) {
        const bool do1 = (it < TSEQ);
        const bool doh = (it >= 1);
        const short* rd1 = h1buf[(it & 1) ^ 1];  // h1(it-1)
        const short* rd2 = h2buf[it & 1];        // h2(it-2)
        short* wr1 = h1buf[it & 1];              // h1(it)
        short* wr2 = h2buf[(it & 1) ^ 1];        // h2(it-1)

        // ---- stage h1 panel (bypass) + x slice; preload first W chunks ----
        if (doh) issue_panel(rd1 + (long)R0 * 512);
        if (do1) {
            const float* xit = x + (long)it * POSE_D;
            for (int idx = tid; idx < 64 * POSE_D; idx += 512) {
                const int r = idx / POSE_D;
                const int c = idx - r * POSE_D;
                lds[XOFF + r * 64 + (((c >> 3) ^ (r & 7)) << 3) + (c & 7)] =
                    f2bf(xit[(long)(R0 + r) * (TSEQ * POSE_D) + c]);
            }
        }
        if (cs == 0) {
            if (do1) {
                const short* P = M1 + (long)((e0 * 4 + es) * 8) * 512 + lane * 8;
#pragma unroll
                for (int i = 0; i < 8; ++i) rW0[i] = *(const bf16x8*)(P + i * 512);
                if (doh) loadW(sWhh1, 0, rW1);
            }
        } else if (doh) {
            loadW(sWih2, 0, rW0);
            loadW(sWih2, 1, rW1);
        }
#pragma unroll
        for (int ri = 0; ri < 4; ++ri)
#pragma unroll
            for (int g = 0; g < 4; ++g) acc[ri][g] = {0.f, 0.f, 0.f, 0.f};
        if (doh) write_panel(AOFF);
        __syncthreads();

        // ---- phase 1: issue h2 panel early, both cells consume h1 panel ----
        if (doh) issue_panel(rd2 + (long)R0 * 512);  // latency hides under MFMA
        if (cs == 0) {
            if (do1) {
                do_x(rW0);  // gates1 += x(it) @ M1^T
                if (doh) {
#pragma unroll 1
                    for (int k = 0; k < 8; ++k) {  // gates1 += h1 @ Whh1^T
                        bf16x8(&buf)[8] = (k & 1) ? rW0 : rW1;
                        do_chunk(k, buf, AOFF);
                        if (k + 2 < 8) loadW(sWhh1, k + 2, buf);
                    }
                }
            }
        } else if (doh) {
#pragma unroll 1
            for (int k = 0; k < 8; ++k) {  // gates2 += h1 @ Wih2^T
                bf16x8(&buf)[8] = (k & 1) ? rW1 : rW0;
                do_chunk(k, buf, AOFF);
                if (k + 2 < 8) loadW(sWih2, k + 2, buf);
            }
        }
        if (cs == 1 && doh) {
            loadW(sWhh2, 0, rW0);
            loadW(sWhh2, 1, rW1);
        }
        if (doh) write_panel(BOFF);  // h2 panel into region B
        __syncthreads();

        // ---- phase 2: cs1 finishes cell2 while cs0 writes cell1's state ----
        if (cs == 0) {
            if (do1) epilogue(bias1, wr1, nullptr);  // c1 stays in VGPRs
        } else if (doh) {
#pragma unroll 1
            for (int k = 0; k < 8; ++k) {  // gates2 += h2 @ Whh2^T
                bf16x8(&buf)[8] = (k & 1) ? rW1 : rW0;
                do_chunk(k, buf, BOFF);
                if (k + 2 < 8) loadW(sWhh2, k + 2, buf);
            }
            epilogue(bias2, wr2, (it == TSEQ) ? c2out : nullptr);
        }

        // ---- grid barrier (no L2 flush/invalidate; W stays resident) ----
        if (it < TSEQ) {
            asm volatile("s_waitcnt vmcnt(0)" ::: "memory");  // h stores at L3
            __syncthreads();
            if (tid == 0) {
                __hip_atomic_fetch_add(cnt, 1u, __ATOMIC_RELAXED,
                                       __HIP_MEMORY_SCOPE_AGENT);
                const unsigned tgt = 256u * (unsigned)(it + 1);
                while (__hip_atomic_load(cnt, __ATOMIC_RELAXED,
                                         __HIP_MEMORY_SCOPE_AGENT) < tgt)
                    __builtin_amdgcn_s_sleep(2);
            }
            __syncthreads();
        }
    }
}

// ---------------- per-cell kernel (decoder), from R8 ----------------
template <bool HAS_X, bool TWO_H, int NP>
__global__ __launch_bounds__(512, 2) void lstm_cell_kernel(
    const float* __restrict__ xptr, const short* __restrict__ M1,
    const short* __restrict__ A1, const short* __restrict__ W1,
    const short* __restrict__ A2, const short* __restrict__ W2,
    const float* __restrict__ bias, float* __restrict__ c_io,
    short* __restrict__ h_out, float* __restrict__ hf_out) {
    __shared__ __align__(16) short lds[HAS_X ? 73728 : 65536];
    const int tid = threadIdx.x;
    const int lane = tid & 63;
    const int wv = tid >> 6;
    const int es2 = wv & 1;
    const int rb = (wv >> 1) & 1;
    const int kg = wv >> 2;
    const int m = lane & 15;
    const int q = lane >> 4;
    const int e16 = blockIdx.x & 15;
    const int R0 = (blockIdx.x >> 4) * 128;
    const int e0 = e16 >> 1;
    const int es = (e16 & 1) * 2 + es2;
    constexpr int PH = NP * 8;
    constexpr int AOFF = HAS_X ? 8192 : 0;

    floatx4 acc[4][4];
#pragma unroll
    for (int ri = 0; ri < 4; ++ri)
#pragma unroll
        for (int g = 0; g < 4; ++g) acc[ri][g] = {0.f, 0.f, 0.f, 0.f};

    bf16x8 rW0[8], rW1[8];

    auto loadW = [&](const short* __restrict__ W, int kcp, bf16x8(&w_)[8]) {
        const short* P = W + (long)((e0 * 16 + kcp) * 4 + es) * 4096 + lane * 8;
#pragma unroll
        for (int i = 0; i < 8; ++i) w_[i] = *(const bf16x8*)(P + i * 512);
    };
    auto loadM1 = [&](bf16x8(&w_)[8]) {
        const short* P = M1 + (long)((e0 * 4 + es) * 8) * 512 + lane * 8;
#pragma unroll
        for (int i = 0; i < 8; ++i) w_[i] = *(const bf16x8*)(P + i * 512);
    };
    auto do_chunk = [&](int kcp, bf16x8(&w_)[8]) {
        const int k8 = (kcp & 7) * 8;
#pragma unroll
        for (int kk = 0; kk < 2; ++kk) {
            bf16x8 a[4];
#pragma unroll
            for (int ri = 0; ri < 4; ++ri) {
                const int row = rb * 64 + ri * 16 + m;
                a[ri] = *(const bf16x8*)(lds + AOFF + row * 512 +
                                         ((k8 | (((kk * 4 + q) ^ row) & 7)) << 3));
            }
#pragma unroll
            for (int ri = 0; ri < 4; ++ri)
#pragma unroll
                for (int g = 0; g < 4; ++g)
                    acc[ri][g] = __builtin_amdgcn_mfma_f32_16x16x32_bf16(
                        a[ri], w_[g * 2 + kk], acc[ri][g], 0, 0, 0);
        }
    };
    auto do_x = [&](bf16x8(&w_)[8]) {
#pragma unroll
        for (int kk = 0; kk < 2; ++kk) {
            bf16x8 a[4];
#pragma unroll
            for (int ri = 0; ri < 4; ++ri) {
                const int row = rb * 64 + ri * 16 + m;
                a[ri] = *(const bf16x8*)(lds + row * 64 + (((kk * 4 + q) ^ (row & 7)) << 3));
            }
#pragma unroll
            for (int ri = 0; ri < 4; ++ri)
#pragma unroll
                for (int g = 0; g < 4; ++g)
                    acc[ri][g] = __builtin_amdgcn_mfma_f32_16x16x32_bf16(
                        a[ri], w_[g * 2 + kk], acc[ri][g], 0, 0, 0);
        }
    };
    auto stageA = [&](const short* __restrict__ G, int dst) {
#pragma unroll
        for (int i = 0; i < 16; ++i) {
            const int u = tid + (i << 9);
            const int r = u >> 6, c = u & 63;
            const shortx8 v = *(const shortx8*)(G + (long)r * 512 + (c << 3));
            *(shortx8*)(lds + dst + r * 512 + (((c & 56) | ((c ^ r) & 7)) << 3)) = v;
        }
    };
    auto loopP = [&](const short* __restrict__ W) {
        int c = kg;
#pragma unroll 1
        for (;;) {
            const int nxt = c + 2;
            if (nxt < PH) loadW(W, nxt, rW1);
            do_chunk(c, rW0);
            c = nxt;
            if (c >= PH) break;
            const int nx2 = c + 2;
            if (nx2 < PH) loadW(W, nx2, rW0);
            do_chunk(c, rW1);
            c = nx2;
            if (c >= PH) break;
        }
    };

    if constexpr (HAS_X) {
        constexpr int NT = 1 + PH;
        floatx4 z = {0.f, 0.f, 0.f, 0.f};
        *(floatx4*)(lds + tid * 16) = z;
        *(floatx4*)(lds + tid * 16 + 8) = z;
        stageA(A1 + (long)R0 * 512, AOFF);
        __syncthreads();
        for (int idx = tid; idx < 128 * POSE_D; idx += 512) {
            const int r = idx / POSE_D;
            const int c = idx - r * POSE_D;
            lds[r * 64 + (((c >> 3) ^ (r & 7)) << 3) + (c & 7)] =
                f2bf(xptr[(long)(R0 + r) * (TSEQ * POSE_D) + c]);
        }
        if (kg == 0) loadM1(rW0);
        else loadW(W1, 0, rW0);
        __syncthreads();
        int c = kg;
#pragma unroll 1
        for (;;) {
            const int nxt = c + 2;
            if (nxt < NT) loadW(W1, nxt - 1, rW1);
            if (c == 0) do_x(rW0);
            else do_chunk(c - 1, rW0);
            c = nxt;
            if (c >= NT) break;
            const int nx2 = c + 2;
            if (nx2 < NT) loadW(W1, nx2 - 1, rW0);
            do_chunk(c - 1, rW1);
            c = nx2;
            if (c >= NT) break;
        }
    } else {
        stageA(A1 + (long)R0 * 512, AOFF);
        loadW(W1, kg, rW0);
        __syncthreads();
        loopP(W1);
        if constexpr (TWO_H) {
            __syncthreads();
            stageA(A2 + (long)R0 * 512, AOFF);
            loadW(W2, kg, rW0);
            __syncthreads();
            loopP(W2);
        }
    }

    __syncthreads();
    float* ldsf = (float*)lds;
    const int L = (rb * 2 + es2) * 64 + lane;
    if (kg == 1) {
#pragma unroll
        for (int ri = 0; ri < 4; ++ri)
#pragma unroll
            for (int g = 0; g < 4; ++g) {
                const int f4 = ri * 4 + g;
                *(floatx4*)(ldsf + L * 68 + ((f4 ^ m) << 2)) = acc[ri][g];
            }
    }
    __syncthreads();
    if (kg == 0) {
#pragma unroll
        for (int ri = 0; ri < 4; ++ri)
#pragma unroll
            for (int g = 0; g < 4; ++g) {
                const int f4 = ri * 4 + g;
                acc[ri][g] += *(const floatx4*)(ldsf + L * 68 + ((f4 ^ m) << 2));
            }
        const int e = e16 * 32 + es2 * 16 + m;
        const float bi = bias[e];
        const float bfv = bias[512 + e];
        const float bg = bias[1024 + e];
        const float bo = bias[1536 + e];
#pragma unroll
        for (int ri = 0; ri < 4; ++ri) {
#pragma unroll
            for (int rg = 0; rg < 4; ++rg) {
                const int br = R0 + rb * 64 + ri * 16 + q * 4 + rg;
                const long cidx = (long)br * EDIM + e;
                const float iv = fsig(acc[ri][0][rg] + bi);
                const float fv = fsig(acc[ri][1][rg] + bfv);
                const float gv = ftanh(acc[ri][2][rg] + bg);
                const float ov = fsig(acc[ri][3][rg] + bo);
                const float cn = fv * c_io[cidx] + iv * gv;
                c_io[cidx] = cn;
                const float hv = ov * ftanh(cn);
                h_out[cidx] = f2bf(hv);
                if (hf_out) hf_out[cidx] = hv;
            }
        }
    }
}

__global__ __launch_bounds__(256) void zero_kernel(unsigned int* __restrict__ p, int n) {
    int i = blockIdx.x * 256 + threadIdx.x;
    const int stride = gridDim.x * 256;
    for (; i < n; i += stride) p[i] = 0u;
}

__global__ __launch_bounds__(256) void prep_bias(
    const float* __restrict__ bih1, const float* __restrict__ bhh1,
    const float* __restrict__ Wih1, const float* __restrict__ encb,
    const float* __restrict__ bih2, const float* __restrict__ bhh2,
    const float* __restrict__ dbih, const float* __restrict__ dbhh,
    float* __restrict__ bias1, float* __restrict__ bias2, float* __restrict__ biasd) {
    const int n = blockIdx.x * 256 + threadIdx.x;
    if (n >= 2048) return;
    float s = bih1[n] + bhh1[n];
    const float* wr = Wih1 + (long)n * EDIM;
    for (int j = 0; j < EDIM; ++j) s += wr[j] * encb[j];
    bias1[n] = s;
    bias2[n] = bih2[n] + bhh2[n];
    biasd[n] = dbih[n] + dbhh[n];
}

// Swizzle fp32 W[2048x512] (+optional addend) into hi|lo bf16 frag-stream;
// nkc limits chunk planes written (8 = hi only, 16 = hi+lo).
__global__ __launch_bounds__(256) void swizzle_w(const float* __restrict__ a,
                                                 const float* __restrict__ b,
                                                 short* __restrict__ o, int nkc) {
    const int idx = blockIdx.x * 256 + threadIdx.x;
    if (idx >= 262144) return;
    const int lane = idx & 63, kk = (idx >> 6) & 1, g = (idx >> 7) & 3;
    const int w = (idx >> 9) & 3, kc = (idx >> 11) & 15, e0 = idx >> 15;
    if (kc >= nkc) return;
    const int row = g * 512 + e0 * 64 + w * 16 + (lane & 15);
    const int ks = (kc & 7) * 64 + kk * 32 + (lane >> 4) * 8;
    const bool lo = kc >= 8;
    shortx8 outv;
#pragma unroll
    for (int j = 0; j < 8; ++j) {
        const long si = (long)row * EDIM + ks + j;
        const float v = b ? (a[si] + b[si]) : a[si];
        const short hi = f2bf(v);
        outv[j] = lo ? f2bf(v - bf2f(hi)) : hi;
    }
    *(shortx8*)(o + (long)idx * 8) = outv;
}

__global__ __launch_bounds__(256) void swizzle_M1(const float* __restrict__ Wih1,
                                                  const float* __restrict__ encW,
                                                  short* __restrict__ o) {
    const int idx = blockIdx.x * 256 + threadIdx.x;
    if (idx >= 131072) return;
    const int u = idx >> 3, j = idx & 7;
    const int lane = u & 63, kk = (u >> 6) & 1, g = (u >> 7) & 3;
    const int w = (u >> 9) & 3, e0 = u >> 11;
    const int row = g * 512 + e0 * 64 + w * 16 + (lane & 15);
    const int k = kk * 32 + (lane >> 4) * 8 + j;
    float s = 0.f;
    if (k < POSE_D) {
        const float* wr = Wih1 + (long)row * EDIM;
        for (int jj = 0; jj < EDIM; ++jj) s += wr[jj] * encW[jj * POSE_D + k];
    }
    o[(long)u * 8 + j] = f2bf(s);
}

__global__ __launch_bounds__(64) void out_proj(const float* __restrict__ hf,
                                               const float* __restrict__ W,
                                               const float* __restrict__ bias,
                                               float* __restrict__ out, int f) {
    const int b = blockIdx.x;
    __shared__ float hrow[EDIM];
    const int lane = threadIdx.x;
    *(floatx4*)(hrow + lane * 8) = *(const floatx4*)(hf + (long)b * EDIM + lane * 8);
    *(floatx4*)(hrow + lane * 8 + 4) = *(const floatx4*)(hf + (long)b * EDIM + lane * 8 + 4);
    __syncthreads();
    if (lane < POSE_D) {
        float acc = bias[lane];
        const float* wr = W + (long)lane * EDIM;
        for (int e = 0; e < EDIM; e += 4) {
            const floatx4 wv = *(const floatx4*)(wr + e);
            acc += hrow[e] * wv[0] + hrow[e + 1] * wv[1] + hrow[e + 2] * wv[2] + hrow[e + 3] * wv[3];
        }
        out[((long)b * FUT + f) * POSE_D + lane] = acc;
    }
}

extern "C" void kernel_launch(void* const* d_in, const int* in_sizes, int n_in,
                              void* d_out, int out_size, void* d_ws, size_t ws_size,
                              hipStream_t stream) {
    const float* x = (const float*)d_in[0];
    const float* encW = (const float*)d_in[1];
    const float* encb = (const float*)d_in[2];
    const float* Wih1 = (const float*)d_in[3];
    const float* Whh1 = (const float*)d_in[4];
    const float* bih1 = (const float*)d_in[5];
    const float* bhh1 = (const float*)d_in[6];
    const float* Wih2 = (const float*)d_in[7];
    const float* Whh2 = (const float*)d_in[8];
    const float* bih2 = (const float*)d_in[9];
    const float* bhh2 = (const float*)d_in[10];
    const float* dWih = (const float*)d_in[11];
    const float* dWhh = (const float*)d_in[12];
    const float* dbih = (const float*)d_in[13];
    const float* dbhh = (const float*)d_in[14];
    const float* oW = (const float*)d_in[15];
    const float* ob = (const float*)d_in[16];
    float* out = (float*)d_out;

    char* ws = (char*)d_ws;
    size_t off = 0;
    auto alloc = [&](size_t bytes) -> char* {
        char* p = ws + off;
        off = (off + bytes + 255) & ~(size_t)255;
        return p;
    };
    const size_t HB = (size_t)BDIM * EDIM * 2;
    const size_t CB = (size_t)BDIM * EDIM * 4;
    const size_t WSZ = (size_t)262144 * 16;
    // zero-region (contiguous): h2b (read as h2(-1) zeros), barrier counter
    short* h2b = (short*)alloc(HB);
    unsigned int* cnt = (unsigned int*)alloc(256);
    short* h1a = (short*)alloc(HB);
    short* h1b = (short*)alloc(HB);
    short* h2a = (short*)alloc(HB);
    float* c2 = (float*)alloc(CB);
    float* hf0 = (float*)alloc(CB);
    float* hf1 = (float*)alloc(CB);
    short* M1 = (short*)alloc((size_t)16384 * 16);
    short* sWhh1 = (short*)alloc(WSZ);
    short* sWih2 = (short*)alloc(WSZ);
    short* sWhh2 = (short*)alloc(WSZ);
    short* sdWhh = (short*)alloc(WSZ);
    short* sWsum = (short*)alloc(WSZ);
    float* bias1 = (float*)alloc(2048 * 4);
    float* bias2 = (float*)alloc(2048 * 4);
    float* biasd = (float*)alloc(2048 * 4);
    (void)ws_size; (void)in_sizes; (void)n_in; (void)out_size;

    zero_kernel<<<2048, 256, 0, stream>>>((unsigned int*)h2b, (int)((HB + 256) / 4));
    prep_bias<<<8, 256, 0, stream>>>(bih1, bhh1, Wih1, encb, bih2, bhh2, dbih, dbhh,
                                     bias1, bias2, biasd);
    swizzle_M1<<<512, 256, 0, stream>>>(Wih1, encW, M1);
    swizzle_w<<<1024, 256, 0, stream>>>(Whh1, nullptr, sWhh1, 8);
    swizzle_w<<<1024, 256, 0, stream>>>(Wih2, nullptr, sWih2, 8);
    swizzle_w<<<1024, 256, 0, stream>>>(Whh2, nullptr, sWhh2, 8);
    swizzle_w<<<1024, 256, 0, stream>>>(dWhh, nullptr, sdWhh, 16);
    swizzle_w<<<1024, 256, 0, stream>>>(dWih, dWhh, sWsum, 16);

    // ---- whole encoder recurrence: one persistent cooperative kernel ----
    {
        void* kargs[] = {&x,   &M1,  &sWhh1, &sWih2, &sWhh2, &bias1, &bias2,
                         &h1a, &h1b, &h2a,   &h2b,   &c2,    &cnt};
        if (hipLaunchCooperativeKernel((void*)seq_persistent, dim3(256), dim3(512),
                                       kargs, 0, stream) != hipSuccess) {
            // grid=256, 136KB LDS -> 1 block/CU -> co-resident by construction
            seq_persistent<<<dim3(256), dim3(512), 0, stream>>>(
                x, M1, sWhh1, sWih2, sWhh2, bias1, bias2, h1a, h1b, h2a, h2b, c2, cnt);
        }
    }
    // h2(99) is in h2b (written at it=100); c2(99) in c2.

    dim3 grid(256), blk(512);
    // decoder (split weights): bf16 ping-pong + fp32 copies for out_proj
    short* hd0 = h1a;
    short* hd1 = h1b;
    lstm_cell_kernel<false, false, 2><<<grid, blk, 0, stream>>>(
        nullptr, nullptr, h2b, sdWhh, nullptr, nullptr, biasd, c2, hd0, hf0);
    out_proj<<<BDIM, 64, 0, stream>>>(hf0, oW, ob, out, 0);
    short *dp = hd0, *dn = hd1;
    float *fp = hf0, *fn = hf1;
    for (int f = 1; f < FUT; ++f) {
        lstm_cell_kernel<false, false, 2><<<grid, blk, 0, stream>>>(
            nullptr, nullptr, dp, sWsum, nullptr, nullptr, biasd, c2, dn, fn);
        out_proj<<<BDIM, 64, 0, stream>>>(fn, oW, ob, out, f);
        short* tt = dp; dp = dn; dn = tt;
        float* tf = fp; fp = fn; fn = tf;
    }
}